// Round 4
// baseline (691.135 us; speedup 1.0000x reference)
//
#include <hip/hip_runtime.h>

// GCN encoder, CSR aggregation with separable norm + bf16 gather tables.
//   dinv[i] = rsqrt(deg_in[i]+1)
//   T1 = bf16( dinv * (x@W1) )                       [gemm1, fused scale+quant]
//   T2 = bf16( dinv * relu( dinv*aggsum(T1) + b1 ) ) [agg<0>]
//   Hagg = dinv * aggsum(T2)                         [agg<1>, fp32]
//   mu = Hagg@Wmu+bmu ; ls = Hagg@Wls+bls            [fused dual gemm]
// CSR build uses 128-node buckets: bucket segment bounds ARE rowptr[b*128],
// so bucket-sort needs no extra histogram/scan, and final placement writes
// stay inside an ~8KB window (no write-allocate thrash).

using uint = unsigned int;

static constexpr int FEAT = 64;
static constexpr int CHUNK = 2048;
static constexpr int BN = 128;       // nodes per bucket

static __device__ __forceinline__ ushort f2bf(float f) {
    uint u = __float_as_uint(f);
    u += 0x7FFFu + ((u >> 16) & 1u);
    return (ushort)(u >> 16);
}
static __device__ __forceinline__ float bf2f(ushort b) {
    return __uint_as_float(((uint)b) << 16);
}

__global__ void deg_count_kernel(const int* __restrict__ dst, int* __restrict__ deg, int E) {
    int e = blockIdx.x * 256 + threadIdx.x;
    if (e < E) atomicAdd(&deg[dst[e]], 1);
}

__global__ void dinv_kernel(const int* __restrict__ deg, float* __restrict__ dinv, int n) {
    int i = blockIdx.x * 256 + threadIdx.x;
    if (i < n) dinv[i] = rsqrtf((float)deg[i] + 1.0f);
}

__global__ void chunk_sum_kernel(const int* __restrict__ deg, int* __restrict__ csum, int n) {
    __shared__ int s[256];
    int base = blockIdx.x * CHUNK;
    int t = 0;
    for (int j = threadIdx.x; j < CHUNK; j += 256) { int i = base + j; t += (i < n) ? deg[i] : 0; }
    s[threadIdx.x] = t; __syncthreads();
    for (int off = 128; off > 0; off >>= 1) {
        if (threadIdx.x < off) s[threadIdx.x] += s[threadIdx.x + off];
        __syncthreads();
    }
    if (threadIdx.x == 0) csum[blockIdx.x] = s[0];
}

__global__ void scan_chunk_kernel(int* __restrict__ csum, int nchunks,
                                  int* __restrict__ rowptr, int n, int E) {
    if (blockIdx.x == 0 && threadIdx.x == 0) {
        int acc = 0;
        for (int i = 0; i < nchunks; ++i) { int v = csum[i]; csum[i] = acc; acc += v; }
        rowptr[n] = E;
    }
}

__global__ void rowptr_kernel(const int* __restrict__ deg, const int* __restrict__ csum,
                              int* __restrict__ rowptr, int n) {
    __shared__ int s[256];
    int base = blockIdx.x * CHUNK;
    int tb = base + threadIdx.x * 8;
    int v[8]; int tsum = 0;
#pragma unroll
    for (int j = 0; j < 8; ++j) { int i = tb + j; v[j] = (i < n) ? deg[i] : 0; tsum += v[j]; }
    s[threadIdx.x] = tsum; __syncthreads();
    for (int off = 1; off < 256; off <<= 1) {
        int t = (threadIdx.x >= (unsigned)off) ? s[threadIdx.x - off] : 0;
        __syncthreads();
        s[threadIdx.x] += t;
        __syncthreads();
    }
    int excl = s[threadIdx.x] - tsum + csum[blockIdx.x];
#pragma unroll
    for (int j = 0; j < 8; ++j) { int i = tb + j; if (i < n) rowptr[i] = excl; excl += v[j]; }
}

// bcur[b] = rowptr[b*BN]  (bucket write cursors seeded from CSR offsets)
__global__ void bcur_init_kernel(const int* __restrict__ rowptr, int* __restrict__ bcur, int nb) {
    int b = blockIdx.x * 256 + threadIdx.x;
    if (b < nb) bcur[b] = rowptr[b * BN];
}

// Phase A: scatter (src,dst) to bucket-sorted order. Per-bucket streams are
// monotone+dense -> full-line writes, no thrash.
__global__ void bucket_scatter_kernel(const int* __restrict__ src, const int* __restrict__ dst,
                                      int* __restrict__ bcur, int2* __restrict__ bpair, int E) {
    int e = blockIdx.x * 256 + threadIdx.x;
    if (e >= E) return;
    int s = src[e], d = dst[e];
    int pos = atomicAdd(&bcur[d >> 7], 1);
    bpair[pos] = make_int2(s, d);
}

// Phase B: one block per bucket; LDS cursors; final ssrc writes stay in the
// bucket's contiguous CSR window.
__global__ __launch_bounds__(256) void place_kernel(const int2* __restrict__ bpair,
                                                    const int* __restrict__ rowptr,
                                                    int* __restrict__ ssrc, int n) {
    __shared__ int cur[BN];
    __shared__ int seg[2];
    int base = blockIdx.x * BN;
    if (threadIdx.x < BN) {
        int node = base + threadIdx.x;
        cur[threadIdx.x] = rowptr[node < n ? node : n];
    }
    if (threadIdx.x == 0) {
        seg[0] = rowptr[base];
        int e = base + BN; seg[1] = rowptr[e < n ? e : n];
    }
    __syncthreads();
    for (int p = seg[0] + (int)threadIdx.x; p < seg[1]; p += 256) {
        int2 e = bpair[p];
        int pos = atomicAdd(&cur[e.y - base], 1);
        ssrc[pos] = e.x;
    }
}

// T1[row][c] = bf16(dinv[row] * (X@W1)[row][c]).  64-row block tile; W and X^T
// staged in LDS; thread computes 4 rows x 4 cols.
__global__ __launch_bounds__(256) void gemm1_kernel(const float* __restrict__ X,
                                                    const float* __restrict__ W,
                                                    const float* __restrict__ dinv,
                                                    ushort* __restrict__ T1, int n) {
    __shared__ float Ws[128 * 64];
    __shared__ float Xs[128 * 64];
    int tid = threadIdx.x;
    int rowbase = blockIdx.x * 64;
    {
        const float4* Wv = (const float4*)W;
        float4* Wsv = (float4*)Ws;
#pragma unroll
        for (int j = 0; j < 8; ++j) Wsv[tid + 256 * j] = Wv[tid + 256 * j];
    }
    {
        int k4 = (tid & 31) * 4;
        int r0 = tid >> 5;
#pragma unroll
        for (int j = 0; j < 8; ++j) {
            int r = r0 + 8 * j;
            int row = rowbase + r;
            float4 v = make_float4(0.f, 0.f, 0.f, 0.f);
            if (row < n) v = *(const float4*)(X + (size_t)row * 128 + k4);
            Xs[(k4 + 0) * 64 + r] = v.x;
            Xs[(k4 + 1) * 64 + r] = v.y;
            Xs[(k4 + 2) * 64 + r] = v.z;
            Xs[(k4 + 3) * 64 + r] = v.w;
        }
    }
    __syncthreads();
    int lane = tid & 63;
    int wave = tid >> 6;
    int colq = (lane & 15) * 4;
    int rloc = wave * 16 + (lane >> 4) * 4;
    float acc[4][4];
#pragma unroll
    for (int i = 0; i < 4; ++i)
#pragma unroll
        for (int j = 0; j < 4; ++j) acc[i][j] = 0.f;
#pragma unroll 4
    for (int k = 0; k < 128; ++k) {
        float4 w = *(const float4*)&Ws[k * 64 + colq];
        float x0 = Xs[k * 64 + rloc + 0];
        float x1 = Xs[k * 64 + rloc + 1];
        float x2 = Xs[k * 64 + rloc + 2];
        float x3 = Xs[k * 64 + rloc + 3];
        acc[0][0] = fmaf(x0, w.x, acc[0][0]); acc[0][1] = fmaf(x0, w.y, acc[0][1]);
        acc[0][2] = fmaf(x0, w.z, acc[0][2]); acc[0][3] = fmaf(x0, w.w, acc[0][3]);
        acc[1][0] = fmaf(x1, w.x, acc[1][0]); acc[1][1] = fmaf(x1, w.y, acc[1][1]);
        acc[1][2] = fmaf(x1, w.z, acc[1][2]); acc[1][3] = fmaf(x1, w.w, acc[1][3]);
        acc[2][0] = fmaf(x2, w.x, acc[2][0]); acc[2][1] = fmaf(x2, w.y, acc[2][1]);
        acc[2][2] = fmaf(x2, w.z, acc[2][2]); acc[2][3] = fmaf(x2, w.w, acc[2][3]);
        acc[3][0] = fmaf(x3, w.x, acc[3][0]); acc[3][1] = fmaf(x3, w.y, acc[3][1]);
        acc[3][2] = fmaf(x3, w.z, acc[3][2]); acc[3][3] = fmaf(x3, w.w, acc[3][3]);
    }
#pragma unroll
    for (int i = 0; i < 4; ++i) {
        int row = rowbase + rloc + i;
        if (row < n) {
            float di = dinv[row];
            ushort4 t;
            t.x = f2bf(acc[i][0] * di);
            t.y = f2bf(acc[i][1] * di);
            t.z = f2bf(acc[i][2] * di);
            t.w = f2bf(acc[i][3] * di);
            *(ushort4*)(T1 + (size_t)row * FEAT + colq) = t;
        }
    }
}

// One wave per node; 64 lanes = 64 feats. Gathers 128B bf16 rows, fp32 accum.
// MODE 0: Tout = bf16(dinv*relu(dinv*sum + bias)); MODE 1: Fout = dinv*sum.
template<int MODE>
__global__ __launch_bounds__(256) void agg_kernel(const ushort* __restrict__ T,
                                                  const int* __restrict__ rowptr,
                                                  const int* __restrict__ ssrc,
                                                  const float* __restrict__ dinv,
                                                  const float* __restrict__ bias,
                                                  ushort* __restrict__ Tout,
                                                  float* __restrict__ Fout, int n) {
    int node = blockIdx.x * 4 + (threadIdx.x >> 6);
    if (node >= n) return;
    int f = threadIdx.x & 63;
    int beg = rowptr[node], end = rowptr[node + 1];
    float di = dinv[node];
    float acc = bf2f(T[(size_t)node * FEAT + f]);   // self-loop term
    int p = beg;
    for (; p + 4 <= end; p += 4) {
        int s0 = ssrc[p], s1 = ssrc[p + 1], s2 = ssrc[p + 2], s3 = ssrc[p + 3];
        float v0 = bf2f(T[(size_t)s0 * FEAT + f]);
        float v1 = bf2f(T[(size_t)s1 * FEAT + f]);
        float v2 = bf2f(T[(size_t)s2 * FEAT + f]);
        float v3 = bf2f(T[(size_t)s3 * FEAT + f]);
        acc += (v0 + v1) + (v2 + v3);
    }
    for (; p < end; ++p) acc += bf2f(T[(size_t)ssrc[p] * FEAT + f]);
    if (MODE == 0) {
        float h = fmaf(di, acc, bias[f]);
        h = fmaxf(h, 0.0f);
        Tout[(size_t)node * FEAT + f] = f2bf(h * di);
    } else {
        Fout[(size_t)node * FEAT + f] = di * acc;
    }
}

// mu = H@Wmu+bmu, ls = H@Wls+bls. 64-row tile, both weights + H^T in LDS.
__global__ __launch_bounds__(256) void gemm_dual_kernel(const float* __restrict__ H,
                                                        const float* __restrict__ Wmu,
                                                        const float* __restrict__ bmu,
                                                        const float* __restrict__ Wls,
                                                        const float* __restrict__ bls,
                                                        float* __restrict__ mu,
                                                        float* __restrict__ ls, int n) {
    __shared__ float Wm[64 * 64];
    __shared__ float Wl[64 * 64];
    __shared__ float Xs[64 * 64];
    int tid = threadIdx.x;
    int rowbase = blockIdx.x * 64;
    {
        const float4* a = (const float4*)Wmu;
        const float4* b = (const float4*)Wls;
        float4* as = (float4*)Wm;
        float4* bs = (float4*)Wl;
#pragma unroll
        for (int j = 0; j < 4; ++j) { as[tid + 256 * j] = a[tid + 256 * j]; bs[tid + 256 * j] = b[tid + 256 * j]; }
    }
    {
        int k4 = (tid & 15) * 4;
        int r0 = tid >> 4;
#pragma unroll
        for (int j = 0; j < 4; ++j) {
            int r = r0 + 16 * j;
            int row = rowbase + r;
            float4 v = make_float4(0.f, 0.f, 0.f, 0.f);
            if (row < n) v = *(const float4*)(H + (size_t)row * 64 + k4);
            Xs[(k4 + 0) * 64 + r] = v.x;
            Xs[(k4 + 1) * 64 + r] = v.y;
            Xs[(k4 + 2) * 64 + r] = v.z;
            Xs[(k4 + 3) * 64 + r] = v.w;
        }
    }
    __syncthreads();
    int lane = tid & 63;
    int wave = tid >> 6;
    int colq = (lane & 15) * 4;
    int rloc = wave * 16 + (lane >> 4) * 4;
    float am[4][4], al[4][4];
#pragma unroll
    for (int i = 0; i < 4; ++i)
#pragma unroll
        for (int j = 0; j < 4; ++j) { am[i][j] = 0.f; al[i][j] = 0.f; }
#pragma unroll 4
    for (int k = 0; k < 64; ++k) {
        float4 wm = *(const float4*)&Wm[k * 64 + colq];
        float4 wl = *(const float4*)&Wl[k * 64 + colq];
        float x0 = Xs[k * 64 + rloc + 0];
        float x1 = Xs[k * 64 + rloc + 1];
        float x2 = Xs[k * 64 + rloc + 2];
        float x3 = Xs[k * 64 + rloc + 3];
        am[0][0] = fmaf(x0, wm.x, am[0][0]); am[0][1] = fmaf(x0, wm.y, am[0][1]);
        am[0][2] = fmaf(x0, wm.z, am[0][2]); am[0][3] = fmaf(x0, wm.w, am[0][3]);
        am[1][0] = fmaf(x1, wm.x, am[1][0]); am[1][1] = fmaf(x1, wm.y, am[1][1]);
        am[1][2] = fmaf(x1, wm.z, am[1][2]); am[1][3] = fmaf(x1, wm.w, am[1][3]);
        am[2][0] = fmaf(x2, wm.x, am[2][0]); am[2][1] = fmaf(x2, wm.y, am[2][1]);
        am[2][2] = fmaf(x2, wm.z, am[2][2]); am[2][3] = fmaf(x2, wm.w, am[2][3]);
        am[3][0] = fmaf(x3, wm.x, am[3][0]); am[3][1] = fmaf(x3, wm.y, am[3][1]);
        am[3][2] = fmaf(x3, wm.z, am[3][2]); am[3][3] = fmaf(x3, wm.w, am[3][3]);
        al[0][0] = fmaf(x0, wl.x, al[0][0]); al[0][1] = fmaf(x0, wl.y, al[0][1]);
        al[0][2] = fmaf(x0, wl.z, al[0][2]); al[0][3] = fmaf(x0, wl.w, al[0][3]);
        al[1][0] = fmaf(x1, wl.x, al[1][0]); al[1][1] = fmaf(x1, wl.y, al[1][1]);
        al[1][2] = fmaf(x1, wl.z, al[1][2]); al[1][3] = fmaf(x1, wl.w, al[1][3]);
        al[2][0] = fmaf(x2, wl.x, al[2][0]); al[2][1] = fmaf(x2, wl.y, al[2][1]);
        al[2][2] = fmaf(x2, wl.z, al[2][2]); al[2][3] = fmaf(x2, wl.w, al[2][3]);
        al[3][0] = fmaf(x3, wl.x, al[3][0]); al[3][1] = fmaf(x3, wl.y, al[3][1]);
        al[3][2] = fmaf(x3, wl.z, al[3][2]); al[3][3] = fmaf(x3, wl.w, al[3][3]);
    }
    float4 bm = *(const float4*)&bmu[colq];
    float4 bl = *(const float4*)&bls[colq];
#pragma unroll
    for (int i = 0; i < 4; ++i) {
        int row = rowbase + rloc + i;
        if (row < n) {
            *(float4*)(mu + (size_t)row * 64 + colq) =
                make_float4(am[i][0] + bm.x, am[i][1] + bm.y, am[i][2] + bm.z, am[i][3] + bm.w);
            *(float4*)(ls + (size_t)row * 64 + colq) =
                make_float4(al[i][0] + bl.x, al[i][1] + bl.y, al[i][2] + bl.z, al[i][3] + bl.w);
        }
    }
}

extern "C" void kernel_launch(void* const* d_in, const int* in_sizes, int n_in,
                              void* d_out, int out_size, void* d_ws, size_t ws_size,
                              hipStream_t stream) {
    const float* x   = (const float*)d_in[0];
    const int*   ei  = (const int*)d_in[1];
    const float* W1  = (const float*)d_in[2];
    const float* b1  = (const float*)d_in[3];
    const float* Wmu = (const float*)d_in[4];
    const float* bmu = (const float*)d_in[5];
    const float* Wls = (const float*)d_in[6];
    const float* bls = (const float*)d_in[7];

    const int N = in_sizes[0] / 128;
    const int E = in_sizes[1] / 2;
    const int* src = ei;
    const int* dst = ei + E;

    const int nchunks = (N + CHUNK - 1) / CHUNK;
    const int nb = (N + BN - 1) / BN;

    int*    deg    = (int*)d_ws;                    // N
    float*  dinv   = (float*)(deg + N);             // N
    int*    rowptr = (int*)(dinv + N);              // N+1
    int*    csum   = rowptr + N + 1;                // nchunks (padded)
    int*    bcur   = csum + ((nchunks + 63) & ~63); // nb (padded)
    int*    ssrc   = bcur + ((nb + 63) & ~63);      // E
    int2*   bpair  = (int2*)(ssrc + E);             // E int2
    ushort* T1     = (ushort*)(bpair + E);          // N*64 bf16
    ushort* T2     = T1 + (size_t)N * FEAT;         // N*64 bf16

    float* mu_slot = (float*)d_out;                 // N*64: Hagg then mu (in-place)
    float* ls_slot = mu_slot + (size_t)N * FEAT;    // N*64: ls

    const int TB = 256;
    int grid_e  = (E + TB - 1) / TB;
    int grid_n  = (N + TB - 1) / TB;
    int grid_n4 = (N + 3) / 4;
    int grid_g  = (N + 63) / 64;

    // ---- CSR build ----
    hipMemsetAsync(deg, 0, (size_t)N * sizeof(int), stream);
    deg_count_kernel<<<grid_e, TB, 0, stream>>>(dst, deg, E);
    dinv_kernel<<<grid_n, TB, 0, stream>>>(deg, dinv, N);
    chunk_sum_kernel<<<nchunks, TB, 0, stream>>>(deg, csum, N);
    scan_chunk_kernel<<<1, TB, 0, stream>>>(csum, nchunks, rowptr, N, E);
    rowptr_kernel<<<nchunks, TB, 0, stream>>>(deg, csum, rowptr, N);
    bcur_init_kernel<<<(nb + TB - 1) / TB, TB, 0, stream>>>(rowptr, bcur, nb);
    bucket_scatter_kernel<<<grid_e, TB, 0, stream>>>(src, dst, bcur, bpair, E);
    place_kernel<<<nb, TB, 0, stream>>>(bpair, rowptr, ssrc, N);

    // ---- T1 = bf16(dinv * (x@W1)) ----
    gemm1_kernel<<<grid_g, TB, 0, stream>>>(x, W1, dinv, T1, N);

    // ---- T2 = bf16(dinv * relu(dinv*aggsum(T1) + b1)) ----
    agg_kernel<0><<<grid_n4, TB, 0, stream>>>(T1, rowptr, ssrc, dinv, b1, T2, nullptr, N);

    // ---- Hagg = dinv * aggsum(T2) ----
    agg_kernel<1><<<grid_n4, TB, 0, stream>>>(T2, rowptr, ssrc, dinv, nullptr, nullptr, mu_slot, N);

    // ---- heads ----
    gemm_dual_kernel<<<grid_g, TB, 0, stream>>>(mu_slot, Wmu, bmu, Wls, bls, mu_slot, ls_slot, N);
}

// Round 5
// 246.758 us; speedup vs baseline: 2.8009x; 2.8009x over previous
//
#include <hip/hip_runtime.h>

// GCN encoder, CSR aggregation with separable norm + bf16 gather tables.
//   dinv[i] = rsqrt(deg_in[i]+1)
//   T1 = bf16( dinv * (x@W1) )                       [gemm1, fused scale+quant]
//   T2 = bf16( dinv * relu( dinv*aggsum(T1) + b1 ) ) [agg<0>]
//   Hagg = dinv * aggsum(T2)                         [agg<1>, fp32]
//   mu = Hagg@Wmu+bmu ; ls = Hagg@Wls+bls            [fused dual gemm]
// CSR build: contention-free counting sort. Per-block LDS histograms over
// 256-node buckets -> per-bucket scan over blocks -> private dense (block,
// bucket) regions (packed u32 = src | dlocal<<17) -> per-bucket in-LDS
// count/scan/scatter emitting rowptr, dinv and ssrc. ZERO global atomics.

using uint = unsigned int;

static constexpr int FEAT = 64;
static constexpr int BN = 256;          // nodes per bucket (dlocal = 8 bits)
static constexpr int SORT_BLOCKS = 256; // edge chunks
static constexpr int NB_MAX = 512;      // max buckets supported in LDS

static __device__ __forceinline__ ushort f2bf(float f) {
    uint u = __float_as_uint(f);
    u += 0x7FFFu + ((u >> 16) & 1u);
    return (ushort)(u >> 16);
}
static __device__ __forceinline__ float bf2f(ushort b) {
    return __uint_as_float(((uint)b) << 16);
}

// Phase A: per-block LDS histogram of dst buckets.
__global__ __launch_bounds__(256) void hist_kernel(const int* __restrict__ dst,
                                                   int* __restrict__ hist, int E, int nb) {
    __shared__ int h[NB_MAX];
    for (int i = threadIdx.x; i < nb; i += 256) h[i] = 0;
    __syncthreads();
    int chunk = (E + SORT_BLOCKS - 1) / SORT_BLOCKS;
    int beg = blockIdx.x * chunk;
    int end = min(beg + chunk, E);
    for (int e = beg + (int)threadIdx.x; e < end; e += 256)
        atomicAdd(&h[dst[e] >> 8], 1);
    __syncthreads();
    for (int i = threadIdx.x; i < nb; i += 256) hist[blockIdx.x * nb + i] = h[i];
}

// Phase B1: per-bucket exclusive scan over blocks (in-place) + bucket totals.
__global__ __launch_bounds__(256) void colscan_kernel(int* __restrict__ hist,
                                                      int* __restrict__ btot, int nb) {
    __shared__ int s[256];
    int b = blockIdx.x;
    int t = threadIdx.x;
    int v = hist[t * nb + b];
    s[t] = v; __syncthreads();
    for (int off = 1; off < 256; off <<= 1) {
        int u = (t >= off) ? s[t - off] : 0;
        __syncthreads();
        s[t] += u;
        __syncthreads();
    }
    hist[t * nb + b] = s[t] - v;      // exclusive within bucket
    if (t == 255) btot[b] = s[255];
}

// Phase B2: scan bucket totals -> bbase[0..nb], rowptr[N]=E. (2 elems/thread)
__global__ __launch_bounds__(256) void bbase_kernel(const int* __restrict__ btot,
                                                    int* __restrict__ bbase, int nb,
                                                    int* __restrict__ rowptr, int n, int E) {
    __shared__ int s[256];
    int t = threadIdx.x;
    int i0 = 2 * t, i1 = 2 * t + 1;
    int v0 = (i0 < nb) ? btot[i0] : 0;
    int v1 = (i1 < nb) ? btot[i1] : 0;
    s[t] = v0 + v1; __syncthreads();
    for (int off = 1; off < 256; off <<= 1) {
        int u = (t >= off) ? s[t - off] : 0;
        __syncthreads();
        s[t] += u;
        __syncthreads();
    }
    int excl = s[t] - (v0 + v1);
    if (i0 < nb) bbase[i0] = excl;
    if (i1 < nb) bbase[i1] = excl + v0;
    if (i0 == nb) bbase[nb] = excl;
    else if (i1 == nb) bbase[nb] = excl + v0;
    if (t == 0) rowptr[n] = E;
}

// Phase C: replay chunk, write packed edges to private dense regions.
__global__ __launch_bounds__(256) void sort_scatter_kernel(const int* __restrict__ src,
                                                           const int* __restrict__ dst,
                                                           const int* __restrict__ hist,
                                                           const int* __restrict__ bbase,
                                                           uint* __restrict__ bpk, int E, int nb) {
    __shared__ int cur[NB_MAX];
    int k = blockIdx.x;
    for (int i = threadIdx.x; i < nb; i += 256) cur[i] = bbase[i] + hist[k * nb + i];
    __syncthreads();
    int chunk = (E + SORT_BLOCKS - 1) / SORT_BLOCKS;
    int beg = k * chunk;
    int end = min(beg + chunk, E);
    for (int e = beg + (int)threadIdx.x; e < end; e += 256) {
        int s = src[e], d = dst[e];
        int pos = atomicAdd(&cur[d >> 8], 1);
        bpk[pos] = (uint)s | ((uint)(d & 255) << 17);
    }
}

// Place: one block per bucket. In-LDS count -> scan -> rowptr/dinv/scatter.
__global__ __launch_bounds__(256) void place_kernel(const uint* __restrict__ bpk,
                                                    const int* __restrict__ bbase,
                                                    int* __restrict__ rowptr,
                                                    float* __restrict__ dinv,
                                                    int* __restrict__ ssrc, int n) {
    __shared__ int cnt[BN];
    __shared__ int s[256];
    int b = blockIdx.x;
    int base = b * BN;
    int beg = bbase[b], end = bbase[b + 1];
    cnt[threadIdx.x] = 0;
    __syncthreads();
    for (int p = beg + (int)threadIdx.x; p < end; p += 256)
        atomicAdd(&cnt[bpk[p] >> 17], 1);
    __syncthreads();
    int c = cnt[threadIdx.x];
    s[threadIdx.x] = c; __syncthreads();
    for (int off = 1; off < 256; off <<= 1) {
        int u = (threadIdx.x >= off) ? s[threadIdx.x - off] : 0;
        __syncthreads();
        s[threadIdx.x] += u;
        __syncthreads();
    }
    int excl = beg + s[threadIdx.x] - c;
    __syncthreads();
    cnt[threadIdx.x] = excl;              // becomes the write cursor
    int node = base + threadIdx.x;
    if (node < n) {
        rowptr[node] = excl;
        dinv[node] = rsqrtf((float)c + 1.0f);
    }
    __syncthreads();
    for (int p = beg + (int)threadIdx.x; p < end; p += 256) {
        uint e = bpk[p];
        int pos = atomicAdd(&cnt[e >> 17], 1);
        ssrc[pos] = (int)(e & 0x1FFFFu);
    }
}

// T1[row][c] = bf16(dinv[row] * (X@W1)[row][c]).  64-row block tile; W and X^T
// staged in LDS; thread computes 4 rows x 4 cols.
__global__ __launch_bounds__(256) void gemm1_kernel(const float* __restrict__ X,
                                                    const float* __restrict__ W,
                                                    const float* __restrict__ dinv,
                                                    ushort* __restrict__ T1, int n) {
    __shared__ float Ws[128 * 64];
    __shared__ float Xs[128 * 64];
    int tid = threadIdx.x;
    int rowbase = blockIdx.x * 64;
    {
        const float4* Wv = (const float4*)W;
        float4* Wsv = (float4*)Ws;
#pragma unroll
        for (int j = 0; j < 8; ++j) Wsv[tid + 256 * j] = Wv[tid + 256 * j];
    }
    {
        int k4 = (tid & 31) * 4;
        int r0 = tid >> 5;
#pragma unroll
        for (int j = 0; j < 8; ++j) {
            int r = r0 + 8 * j;
            int row = rowbase + r;
            float4 v = make_float4(0.f, 0.f, 0.f, 0.f);
            if (row < n) v = *(const float4*)(X + (size_t)row * 128 + k4);
            Xs[(k4 + 0) * 64 + r] = v.x;
            Xs[(k4 + 1) * 64 + r] = v.y;
            Xs[(k4 + 2) * 64 + r] = v.z;
            Xs[(k4 + 3) * 64 + r] = v.w;
        }
    }
    __syncthreads();
    int lane = tid & 63;
    int wave = tid >> 6;
    int colq = (lane & 15) * 4;
    int rloc = wave * 16 + (lane >> 4) * 4;
    float acc[4][4];
#pragma unroll
    for (int i = 0; i < 4; ++i)
#pragma unroll
        for (int j = 0; j < 4; ++j) acc[i][j] = 0.f;
#pragma unroll 4
    for (int k = 0; k < 128; ++k) {
        float4 w = *(const float4*)&Ws[k * 64 + colq];
        float x0 = Xs[k * 64 + rloc + 0];
        float x1 = Xs[k * 64 + rloc + 1];
        float x2 = Xs[k * 64 + rloc + 2];
        float x3 = Xs[k * 64 + rloc + 3];
        acc[0][0] = fmaf(x0, w.x, acc[0][0]); acc[0][1] = fmaf(x0, w.y, acc[0][1]);
        acc[0][2] = fmaf(x0, w.z, acc[0][2]); acc[0][3] = fmaf(x0, w.w, acc[0][3]);
        acc[1][0] = fmaf(x1, w.x, acc[1][0]); acc[1][1] = fmaf(x1, w.y, acc[1][1]);
        acc[1][2] = fmaf(x1, w.z, acc[1][2]); acc[1][3] = fmaf(x1, w.w, acc[1][3]);
        acc[2][0] = fmaf(x2, w.x, acc[2][0]); acc[2][1] = fmaf(x2, w.y, acc[2][1]);
        acc[2][2] = fmaf(x2, w.z, acc[2][2]); acc[2][3] = fmaf(x2, w.w, acc[2][3]);
        acc[3][0] = fmaf(x3, w.x, acc[3][0]); acc[3][1] = fmaf(x3, w.y, acc[3][1]);
        acc[3][2] = fmaf(x3, w.z, acc[3][2]); acc[3][3] = fmaf(x3, w.w, acc[3][3]);
    }
#pragma unroll
    for (int i = 0; i < 4; ++i) {
        int row = rowbase + rloc + i;
        if (row < n) {
            float di = dinv[row];
            ushort4 t;
            t.x = f2bf(acc[i][0] * di);
            t.y = f2bf(acc[i][1] * di);
            t.z = f2bf(acc[i][2] * di);
            t.w = f2bf(acc[i][3] * di);
            *(ushort4*)(T1 + (size_t)row * FEAT + colq) = t;
        }
    }
}

// One wave per node; 64 lanes = 64 feats. Gathers 128B bf16 rows, fp32 accum.
// MODE 0: Tout = bf16(dinv*relu(dinv*sum + bias)); MODE 1: Fout = dinv*sum.
template<int MODE>
__global__ __launch_bounds__(256) void agg_kernel(const ushort* __restrict__ T,
                                                  const int* __restrict__ rowptr,
                                                  const int* __restrict__ ssrc,
                                                  const float* __restrict__ dinv,
                                                  const float* __restrict__ bias,
                                                  ushort* __restrict__ Tout,
                                                  float* __restrict__ Fout, int n) {
    int node = blockIdx.x * 4 + (threadIdx.x >> 6);
    if (node >= n) return;
    int f = threadIdx.x & 63;
    int beg = rowptr[node], end = rowptr[node + 1];
    float di = dinv[node];
    float acc = bf2f(T[(size_t)node * FEAT + f]);   // self-loop term
    int p = beg;
    for (; p + 4 <= end; p += 4) {
        int s0 = ssrc[p], s1 = ssrc[p + 1], s2 = ssrc[p + 2], s3 = ssrc[p + 3];
        float v0 = bf2f(T[(size_t)s0 * FEAT + f]);
        float v1 = bf2f(T[(size_t)s1 * FEAT + f]);
        float v2 = bf2f(T[(size_t)s2 * FEAT + f]);
        float v3 = bf2f(T[(size_t)s3 * FEAT + f]);
        acc += (v0 + v1) + (v2 + v3);
    }
    for (; p < end; ++p) acc += bf2f(T[(size_t)ssrc[p] * FEAT + f]);
    if (MODE == 0) {
        float h = fmaf(di, acc, bias[f]);
        h = fmaxf(h, 0.0f);
        Tout[(size_t)node * FEAT + f] = f2bf(h * di);
    } else {
        Fout[(size_t)node * FEAT + f] = di * acc;
    }
}

// mu = H@Wmu+bmu, ls = H@Wls+bls. 64-row tile, both weights + H^T in LDS.
__global__ __launch_bounds__(256) void gemm_dual_kernel(const float* __restrict__ H,
                                                        const float* __restrict__ Wmu,
                                                        const float* __restrict__ bmu,
                                                        const float* __restrict__ Wls,
                                                        const float* __restrict__ bls,
                                                        float* __restrict__ mu,
                                                        float* __restrict__ ls, int n) {
    __shared__ float Wm[64 * 64];
    __shared__ float Wl[64 * 64];
    __shared__ float Xs[64 * 64];
    int tid = threadIdx.x;
    int rowbase = blockIdx.x * 64;
    {
        const float4* a = (const float4*)Wmu;
        const float4* b = (const float4*)Wls;
        float4* as = (float4*)Wm;
        float4* bs = (float4*)Wl;
#pragma unroll
        for (int j = 0; j < 4; ++j) { as[tid + 256 * j] = a[tid + 256 * j]; bs[tid + 256 * j] = b[tid + 256 * j]; }
    }
    {
        int k4 = (tid & 15) * 4;
        int r0 = tid >> 4;
#pragma unroll
        for (int j = 0; j < 4; ++j) {
            int r = r0 + 16 * j;
            int row = rowbase + r;
            float4 v = make_float4(0.f, 0.f, 0.f, 0.f);
            if (row < n) v = *(const float4*)(H + (size_t)row * 64 + k4);
            Xs[(k4 + 0) * 64 + r] = v.x;
            Xs[(k4 + 1) * 64 + r] = v.y;
            Xs[(k4 + 2) * 64 + r] = v.z;
            Xs[(k4 + 3) * 64 + r] = v.w;
        }
    }
    __syncthreads();
    int lane = tid & 63;
    int wave = tid >> 6;
    int colq = (lane & 15) * 4;
    int rloc = wave * 16 + (lane >> 4) * 4;
    float am[4][4], al[4][4];
#pragma unroll
    for (int i = 0; i < 4; ++i)
#pragma unroll
        for (int j = 0; j < 4; ++j) { am[i][j] = 0.f; al[i][j] = 0.f; }
#pragma unroll 4
    for (int k = 0; k < 64; ++k) {
        float4 wm = *(const float4*)&Wm[k * 64 + colq];
        float4 wl = *(const float4*)&Wl[k * 64 + colq];
        float x0 = Xs[k * 64 + rloc + 0];
        float x1 = Xs[k * 64 + rloc + 1];
        float x2 = Xs[k * 64 + rloc + 2];
        float x3 = Xs[k * 64 + rloc + 3];
        am[0][0] = fmaf(x0, wm.x, am[0][0]); am[0][1] = fmaf(x0, wm.y, am[0][1]);
        am[0][2] = fmaf(x0, wm.z, am[0][2]); am[0][3] = fmaf(x0, wm.w, am[0][3]);
        am[1][0] = fmaf(x1, wm.x, am[1][0]); am[1][1] = fmaf(x1, wm.y, am[1][1]);
        am[1][2] = fmaf(x1, wm.z, am[1][2]); am[1][3] = fmaf(x1, wm.w, am[1][3]);
        am[2][0] = fmaf(x2, wm.x, am[2][0]); am[2][1] = fmaf(x2, wm.y, am[2][1]);
        am[2][2] = fmaf(x2, wm.z, am[2][2]); am[2][3] = fmaf(x2, wm.w, am[2][3]);
        am[3][0] = fmaf(x3, wm.x, am[3][0]); am[3][1] = fmaf(x3, wm.y, am[3][1]);
        am[3][2] = fmaf(x3, wm.z, am[3][2]); am[3][3] = fmaf(x3, wm.w, am[3][3]);
        al[0][0] = fmaf(x0, wl.x, al[0][0]); al[0][1] = fmaf(x0, wl.y, al[0][1]);
        al[0][2] = fmaf(x0, wl.z, al[0][2]); al[0][3] = fmaf(x0, wl.w, al[0][3]);
        al[1][0] = fmaf(x1, wl.x, al[1][0]); al[1][1] = fmaf(x1, wl.y, al[1][1]);
        al[1][2] = fmaf(x1, wl.z, al[1][2]); al[1][3] = fmaf(x1, wl.w, al[1][3]);
        al[2][0] = fmaf(x2, wl.x, al[2][0]); al[2][1] = fmaf(x2, wl.y, al[2][1]);
        al[2][2] = fmaf(x2, wl.z, al[2][2]); al[2][3] = fmaf(x2, wl.w, al[2][3]);
        al[3][0] = fmaf(x3, wl.x, al[3][0]); al[3][1] = fmaf(x3, wl.y, al[3][1]);
        al[3][2] = fmaf(x3, wl.z, al[3][2]); al[3][3] = fmaf(x3, wl.w, al[3][3]);
    }
    float4 bm = *(const float4*)&bmu[colq];
    float4 bl = *(const float4*)&bls[colq];
#pragma unroll
    for (int i = 0; i < 4; ++i) {
        int row = rowbase + rloc + i;
        if (row < n) {
            *(float4*)(mu + (size_t)row * 64 + colq) =
                make_float4(am[i][0] + bm.x, am[i][1] + bm.y, am[i][2] + bm.z, am[i][3] + bm.w);
            *(float4*)(ls + (size_t)row * 64 + colq) =
                make_float4(al[i][0] + bl.x, al[i][1] + bl.y, al[i][2] + bl.z, al[i][3] + bl.w);
        }
    }
}

extern "C" void kernel_launch(void* const* d_in, const int* in_sizes, int n_in,
                              void* d_out, int out_size, void* d_ws, size_t ws_size,
                              hipStream_t stream) {
    const float* x   = (const float*)d_in[0];
    const int*   ei  = (const int*)d_in[1];
    const float* W1  = (const float*)d_in[2];
    const float* b1  = (const float*)d_in[3];
    const float* Wmu = (const float*)d_in[4];
    const float* bmu = (const float*)d_in[5];
    const float* Wls = (const float*)d_in[6];
    const float* bls = (const float*)d_in[7];

    const int N = in_sizes[0] / 128;
    const int E = in_sizes[1] / 2;
    const int* src = ei;
    const int* dst = ei + E;

    const int nb = (N + BN - 1) / BN;   // 391 buckets (<= NB_MAX)

    float*  dinv   = (float*)d_ws;                      // N
    int*    rowptr = (int*)(dinv + N);                  // N+1
    int*    hist   = rowptr + ((N + 1 + 63) & ~63);     // SORT_BLOCKS*nb
    int*    btot   = hist + SORT_BLOCKS * nb;           // nb
    int*    bbase  = btot + ((nb + 63) & ~63);          // nb+1
    int*    ssrc   = bbase + ((nb + 1 + 63) & ~63);     // E
    uint*   bpk    = (uint*)(ssrc + E);                 // E
    ushort* T1     = (ushort*)(bpk + E);                // N*64 bf16
    ushort* T2     = T1 + (size_t)N * FEAT;             // N*64 bf16

    float* mu_slot = (float*)d_out;                     // N*64: Hagg then mu (in-place)
    float* ls_slot = mu_slot + (size_t)N * FEAT;        // N*64: ls

    const int TB = 256;
    int grid_n4 = (N + 3) / 4;
    int grid_g  = (N + 63) / 64;

    // ---- CSR build (no global atomics) ----
    hist_kernel<<<SORT_BLOCKS, TB, 0, stream>>>(dst, hist, E, nb);
    colscan_kernel<<<nb, TB, 0, stream>>>(hist, btot, nb);
    bbase_kernel<<<1, TB, 0, stream>>>(btot, bbase, nb, rowptr, N, E);
    sort_scatter_kernel<<<SORT_BLOCKS, TB, 0, stream>>>(src, dst, hist, bbase, bpk, E, nb);
    place_kernel<<<nb, TB, 0, stream>>>(bpk, bbase, rowptr, dinv, ssrc, N);

    // ---- T1 = bf16(dinv * (x@W1)) ----
    gemm1_kernel<<<grid_g, TB, 0, stream>>>(x, W1, dinv, T1, N);

    // ---- T2 = bf16(dinv * relu(dinv*aggsum(T1) + b1)) ----
    agg_kernel<0><<<grid_n4, TB, 0, stream>>>(T1, rowptr, ssrc, dinv, b1, T2, nullptr, N);

    // ---- Hagg = dinv * aggsum(T2) ----
    agg_kernel<1><<<grid_n4, TB, 0, stream>>>(T2, rowptr, ssrc, dinv, nullptr, nullptr, mu_slot, N);

    // ---- heads ----
    gemm_dual_kernel<<<grid_g, TB, 0, stream>>>(mu_slot, Wmu, bmu, Wls, bls, mu_slot, ls_slot, N);
}

// Round 6
// 245.743 us; speedup vs baseline: 2.8124x; 1.0041x over previous
//
#include <hip/hip_runtime.h>

// GCN encoder, CSR aggregation with separable norm + bf16 gather tables.
//   dinv[i] = rsqrt(deg_in[i]+1)
//   T1 = bf16( dinv * (x@W1) )                       [gemm1, fused scale+quant]
//   T2 = bf16( dinv * relu( dinv*aggsum(T1) + b1 ) ) [agg<0>]
//   Hagg = dinv * aggsum(T2)                         [agg<1>, fp32]
//   mu = Hagg@Wmu+bmu ; ls = Hagg@Wls+bls            [fused dual gemm]
// CSR build: contention-free counting sort (per-block LDS histograms,
// per-bucket scan, private dense regions, per-bucket place). ZERO global atomics.

using uint = unsigned int;

static constexpr int FEAT = 64;
static constexpr int BN = 256;          // nodes per bucket (dlocal = 8 bits)
static constexpr int SORT_BLOCKS = 256; // edge chunks
static constexpr int NB_MAX = 512;      // max buckets supported in LDS

static __device__ __forceinline__ ushort f2bf(float f) {
    uint u = __float_as_uint(f);
    u += 0x7FFFu + ((u >> 16) & 1u);
    return (ushort)(u >> 16);
}
static __device__ __forceinline__ float bf2f(ushort b) {
    return __uint_as_float(((uint)b) << 16);
}

// Phase A: per-block LDS histogram of dst buckets.
__global__ __launch_bounds__(256) void hist_kernel(const int* __restrict__ dst,
                                                   int* __restrict__ hist, int E, int nb) {
    __shared__ int h[NB_MAX];
    for (int i = threadIdx.x; i < nb; i += 256) h[i] = 0;
    __syncthreads();
    int chunk = (E + SORT_BLOCKS - 1) / SORT_BLOCKS;
    int beg = blockIdx.x * chunk;
    int end = min(beg + chunk, E);
    for (int e = beg + (int)threadIdx.x; e < end; e += 256)
        atomicAdd(&h[dst[e] >> 8], 1);
    __syncthreads();
    for (int i = threadIdx.x; i < nb; i += 256) hist[blockIdx.x * nb + i] = h[i];
}

// Phase B1: per-bucket exclusive scan over blocks (in-place) + bucket totals.
__global__ __launch_bounds__(256) void colscan_kernel(int* __restrict__ hist,
                                                      int* __restrict__ btot, int nb) {
    __shared__ int s[256];
    int b = blockIdx.x;
    int t = threadIdx.x;
    int v = hist[t * nb + b];
    s[t] = v; __syncthreads();
    for (int off = 1; off < 256; off <<= 1) {
        int u = (t >= off) ? s[t - off] : 0;
        __syncthreads();
        s[t] += u;
        __syncthreads();
    }
    hist[t * nb + b] = s[t] - v;      // exclusive within bucket
    if (t == 255) btot[b] = s[255];
}

// Phase B2: scan bucket totals -> bbase[0..nb], rowptr[N]=E. (2 elems/thread)
__global__ __launch_bounds__(256) void bbase_kernel(const int* __restrict__ btot,
                                                    int* __restrict__ bbase, int nb,
                                                    int* __restrict__ rowptr, int n, int E) {
    __shared__ int s[256];
    int t = threadIdx.x;
    int i0 = 2 * t, i1 = 2 * t + 1;
    int v0 = (i0 < nb) ? btot[i0] : 0;
    int v1 = (i1 < nb) ? btot[i1] : 0;
    s[t] = v0 + v1; __syncthreads();
    for (int off = 1; off < 256; off <<= 1) {
        int u = (t >= off) ? s[t - off] : 0;
        __syncthreads();
        s[t] += u;
        __syncthreads();
    }
    int excl = s[t] - (v0 + v1);
    if (i0 < nb) bbase[i0] = excl;
    if (i1 < nb) bbase[i1] = excl + v0;
    if (i0 == nb) bbase[nb] = excl;
    else if (i1 == nb) bbase[nb] = excl + v0;
    if (t == 0) rowptr[n] = E;
}

// Phase C: replay chunk, write packed edges to private dense regions.
__global__ __launch_bounds__(256) void sort_scatter_kernel(const int* __restrict__ src,
                                                           const int* __restrict__ dst,
                                                           const int* __restrict__ hist,
                                                           const int* __restrict__ bbase,
                                                           uint* __restrict__ bpk, int E, int nb) {
    __shared__ int cur[NB_MAX];
    int k = blockIdx.x;
    for (int i = threadIdx.x; i < nb; i += 256) cur[i] = bbase[i] + hist[k * nb + i];
    __syncthreads();
    int chunk = (E + SORT_BLOCKS - 1) / SORT_BLOCKS;
    int beg = k * chunk;
    int end = min(beg + chunk, E);
    for (int e = beg + (int)threadIdx.x; e < end; e += 256) {
        int s = src[e], d = dst[e];
        int pos = atomicAdd(&cur[d >> 8], 1);
        bpk[pos] = (uint)s | ((uint)(d & 255) << 17);
    }
}

// Place: one block per bucket. In-LDS count -> scan -> rowptr/dinv/scatter.
__global__ __launch_bounds__(256) void place_kernel(const uint* __restrict__ bpk,
                                                    const int* __restrict__ bbase,
                                                    int* __restrict__ rowptr,
                                                    float* __restrict__ dinv,
                                                    int* __restrict__ ssrc, int n) {
    __shared__ int cnt[BN];
    __shared__ int s[256];
    int b = blockIdx.x;
    int base = b * BN;
    int beg = bbase[b], end = bbase[b + 1];
    cnt[threadIdx.x] = 0;
    __syncthreads();
    for (int p = beg + (int)threadIdx.x; p < end; p += 256)
        atomicAdd(&cnt[bpk[p] >> 17], 1);
    __syncthreads();
    int c = cnt[threadIdx.x];
    s[threadIdx.x] = c; __syncthreads();
    for (int off = 1; off < 256; off <<= 1) {
        int u = (threadIdx.x >= off) ? s[threadIdx.x - off] : 0;
        __syncthreads();
        s[threadIdx.x] += u;
        __syncthreads();
    }
    int excl = beg + s[threadIdx.x] - c;
    __syncthreads();
    cnt[threadIdx.x] = excl;              // becomes the write cursor
    int node = base + threadIdx.x;
    if (node < n) {
        rowptr[node] = excl;
        dinv[node] = rsqrtf((float)c + 1.0f);
    }
    __syncthreads();
    for (int p = beg + (int)threadIdx.x; p < end; p += 256) {
        uint e = bpk[p];
        int pos = atomicAdd(&cnt[e >> 17], 1);
        ssrc[pos] = (int)(e & 0x1FFFFu);
    }
}

// T1[row][c] = bf16(dinv[row] * (X@W1)[row][c]).  64-row block tile; W and X^T
// staged in LDS; thread computes 4 rows x 4 cols; all LDS reads are b128.
__global__ __launch_bounds__(256) void gemm1_kernel(const float* __restrict__ X,
                                                    const float* __restrict__ W,
                                                    const float* __restrict__ dinv,
                                                    ushort* __restrict__ T1, int n) {
    __shared__ float Ws[128 * 64];
    __shared__ float Xs[128 * 64];
    int tid = threadIdx.x;
    int rowbase = blockIdx.x * 64;
    {
        const float4* Wv = (const float4*)W;
        float4* Wsv = (float4*)Ws;
#pragma unroll
        for (int j = 0; j < 8; ++j) Wsv[tid + 256 * j] = Wv[tid + 256 * j];
    }
    {
        int k4 = (tid & 31) * 4;
        int r0 = tid >> 5;
#pragma unroll
        for (int j = 0; j < 8; ++j) {
            int r = r0 + 8 * j;
            int row = rowbase + r;
            float4 v = make_float4(0.f, 0.f, 0.f, 0.f);
            if (row < n) v = *(const float4*)(X + (size_t)row * 128 + k4);
            Xs[(k4 + 0) * 64 + r] = v.x;
            Xs[(k4 + 1) * 64 + r] = v.y;
            Xs[(k4 + 2) * 64 + r] = v.z;
            Xs[(k4 + 3) * 64 + r] = v.w;
        }
    }
    __syncthreads();
    int lane = tid & 63;
    int wave = tid >> 6;
    int colq = (lane & 15) * 4;
    int rloc = wave * 16 + (lane >> 4) * 4;
    float acc[4][4];
#pragma unroll
    for (int i = 0; i < 4; ++i)
#pragma unroll
        for (int j = 0; j < 4; ++j) acc[i][j] = 0.f;
#pragma unroll 4
    for (int k = 0; k < 128; ++k) {
        float4 w = *(const float4*)&Ws[k * 64 + colq];
        float4 xv = *(const float4*)&Xs[k * 64 + rloc];
        acc[0][0] = fmaf(xv.x, w.x, acc[0][0]); acc[0][1] = fmaf(xv.x, w.y, acc[0][1]);
        acc[0][2] = fmaf(xv.x, w.z, acc[0][2]); acc[0][3] = fmaf(xv.x, w.w, acc[0][3]);
        acc[1][0] = fmaf(xv.y, w.x, acc[1][0]); acc[1][1] = fmaf(xv.y, w.y, acc[1][1]);
        acc[1][2] = fmaf(xv.y, w.z, acc[1][2]); acc[1][3] = fmaf(xv.y, w.w, acc[1][3]);
        acc[2][0] = fmaf(xv.z, w.x, acc[2][0]); acc[2][1] = fmaf(xv.z, w.y, acc[2][1]);
        acc[2][2] = fmaf(xv.z, w.z, acc[2][2]); acc[2][3] = fmaf(xv.z, w.w, acc[2][3]);
        acc[3][0] = fmaf(xv.w, w.x, acc[3][0]); acc[3][1] = fmaf(xv.w, w.y, acc[3][1]);
        acc[3][2] = fmaf(xv.w, w.z, acc[3][2]); acc[3][3] = fmaf(xv.w, w.w, acc[3][3]);
    }
#pragma unroll
    for (int i = 0; i < 4; ++i) {
        int row = rowbase + rloc + i;
        if (row < n) {
            float di = dinv[row];
            ushort4 t;
            t.x = f2bf(acc[i][0] * di);
            t.y = f2bf(acc[i][1] * di);
            t.z = f2bf(acc[i][2] * di);
            t.w = f2bf(acc[i][3] * di);
            *(ushort4*)(T1 + (size_t)row * FEAT + colq) = t;
        }
    }
}

// One wave per node; 64 lanes = 64 feats. Gathers 128B bf16 rows, fp32 accum.
// 8-deep unrolled gather pipeline; ssrc read as wave-uniform int4 (p 4-aligned).
// MODE 0: Tout = bf16(dinv*relu(dinv*sum + bias)); MODE 1: Fout = dinv*sum.
template<int MODE>
__global__ __launch_bounds__(256) void agg_kernel(const ushort* __restrict__ T,
                                                  const int* __restrict__ rowptr,
                                                  const int* __restrict__ ssrc,
                                                  const float* __restrict__ dinv,
                                                  const float* __restrict__ bias,
                                                  ushort* __restrict__ Tout,
                                                  float* __restrict__ Fout, int n) {
    int node = blockIdx.x * 4 + (threadIdx.x >> 6);
    if (node >= n) return;
    int f = threadIdx.x & 63;
    int beg = rowptr[node], end = rowptr[node + 1];
    float di = dinv[node];
    float acc = bf2f(T[(size_t)node * FEAT + f]);   // self-loop term
    int p = beg;
    int ahead = (beg + 3) & ~3;                     // align to int4 boundary
    for (int lim = min(ahead, end); p < lim; ++p)
        acc += bf2f(T[(size_t)ssrc[p] * FEAT + f]);
    for (; p + 8 <= end; p += 8) {
        int4 a = *(const int4*)(ssrc + p);
        int4 b = *(const int4*)(ssrc + p + 4);
        float v0 = bf2f(T[(size_t)a.x * FEAT + f]);
        float v1 = bf2f(T[(size_t)a.y * FEAT + f]);
        float v2 = bf2f(T[(size_t)a.z * FEAT + f]);
        float v3 = bf2f(T[(size_t)a.w * FEAT + f]);
        float v4 = bf2f(T[(size_t)b.x * FEAT + f]);
        float v5 = bf2f(T[(size_t)b.y * FEAT + f]);
        float v6 = bf2f(T[(size_t)b.z * FEAT + f]);
        float v7 = bf2f(T[(size_t)b.w * FEAT + f]);
        acc += ((v0 + v1) + (v2 + v3)) + ((v4 + v5) + (v6 + v7));
    }
    if (p + 4 <= end) {
        int4 a = *(const int4*)(ssrc + p);
        float v0 = bf2f(T[(size_t)a.x * FEAT + f]);
        float v1 = bf2f(T[(size_t)a.y * FEAT + f]);
        float v2 = bf2f(T[(size_t)a.z * FEAT + f]);
        float v3 = bf2f(T[(size_t)a.w * FEAT + f]);
        acc += (v0 + v1) + (v2 + v3);
        p += 4;
    }
    for (; p < end; ++p) acc += bf2f(T[(size_t)ssrc[p] * FEAT + f]);
    if (MODE == 0) {
        float h = fmaf(di, acc, bias[f]);
        h = fmaxf(h, 0.0f);
        Tout[(size_t)node * FEAT + f] = f2bf(h * di);
    } else {
        Fout[(size_t)node * FEAT + f] = di * acc;
    }
}

// mu = H@Wmu+bmu, ls = H@Wls+bls. 64-row tile, both weights + H^T in LDS.
__global__ __launch_bounds__(256) void gemm_dual_kernel(const float* __restrict__ H,
                                                        const float* __restrict__ Wmu,
                                                        const float* __restrict__ bmu,
                                                        const float* __restrict__ Wls,
                                                        const float* __restrict__ bls,
                                                        float* __restrict__ mu,
                                                        float* __restrict__ ls, int n) {
    __shared__ float Wm[64 * 64];
    __shared__ float Wl[64 * 64];
    __shared__ float Xs[64 * 64];
    int tid = threadIdx.x;
    int rowbase = blockIdx.x * 64;
    {
        const float4* a = (const float4*)Wmu;
        const float4* b = (const float4*)Wls;
        float4* as = (float4*)Wm;
        float4* bs = (float4*)Wl;
#pragma unroll
        for (int j = 0; j < 4; ++j) { as[tid + 256 * j] = a[tid + 256 * j]; bs[tid + 256 * j] = b[tid + 256 * j]; }
    }
    {
        int k4 = (tid & 15) * 4;
        int r0 = tid >> 4;
#pragma unroll
        for (int j = 0; j < 4; ++j) {
            int r = r0 + 16 * j;
            int row = rowbase + r;
            float4 v = make_float4(0.f, 0.f, 0.f, 0.f);
            if (row < n) v = *(const float4*)(H + (size_t)row * 64 + k4);
            Xs[(k4 + 0) * 64 + r] = v.x;
            Xs[(k4 + 1) * 64 + r] = v.y;
            Xs[(k4 + 2) * 64 + r] = v.z;
            Xs[(k4 + 3) * 64 + r] = v.w;
        }
    }
    __syncthreads();
    int lane = tid & 63;
    int wave = tid >> 6;
    int colq = (lane & 15) * 4;
    int rloc = wave * 16 + (lane >> 4) * 4;
    float am[4][4], al[4][4];
#pragma unroll
    for (int i = 0; i < 4; ++i)
#pragma unroll
        for (int j = 0; j < 4; ++j) { am[i][j] = 0.f; al[i][j] = 0.f; }
#pragma unroll 4
    for (int k = 0; k < 64; ++k) {
        float4 wm = *(const float4*)&Wm[k * 64 + colq];
        float4 wl = *(const float4*)&Wl[k * 64 + colq];
        float4 xv = *(const float4*)&Xs[k * 64 + rloc];
        am[0][0] = fmaf(xv.x, wm.x, am[0][0]); am[0][1] = fmaf(xv.x, wm.y, am[0][1]);
        am[0][2] = fmaf(xv.x, wm.z, am[0][2]); am[0][3] = fmaf(xv.x, wm.w, am[0][3]);
        am[1][0] = fmaf(xv.y, wm.x, am[1][0]); am[1][1] = fmaf(xv.y, wm.y, am[1][1]);
        am[1][2] = fmaf(xv.y, wm.z, am[1][2]); am[1][3] = fmaf(xv.y, wm.w, am[1][3]);
        am[2][0] = fmaf(xv.z, wm.x, am[2][0]); am[2][1] = fmaf(xv.z, wm.y, am[2][1]);
        am[2][2] = fmaf(xv.z, wm.z, am[2][2]); am[2][3] = fmaf(xv.z, wm.w, am[2][3]);
        am[3][0] = fmaf(xv.w, wm.x, am[3][0]); am[3][1] = fmaf(xv.w, wm.y, am[3][1]);
        am[3][2] = fmaf(xv.w, wm.z, am[3][2]); am[3][3] = fmaf(xv.w, wm.w, am[3][3]);
        al[0][0] = fmaf(xv.x, wl.x, al[0][0]); al[0][1] = fmaf(xv.x, wl.y, al[0][1]);
        al[0][2] = fmaf(xv.x, wl.z, al[0][2]); al[0][3] = fmaf(xv.x, wl.w, al[0][3]);
        al[1][0] = fmaf(xv.y, wl.x, al[1][0]); al[1][1] = fmaf(xv.y, wl.y, al[1][1]);
        al[1][2] = fmaf(xv.y, wl.z, al[1][2]); al[1][3] = fmaf(xv.y, wl.w, al[1][3]);
        al[2][0] = fmaf(xv.z, wl.x, al[2][0]); al[2][1] = fmaf(xv.z, wl.y, al[2][1]);
        al[2][2] = fmaf(xv.z, wl.z, al[2][2]); al[2][3] = fmaf(xv.z, wl.w, al[2][3]);
        al[3][0] = fmaf(xv.w, wl.x, al[3][0]); al[3][1] = fmaf(xv.w, wl.y, al[3][1]);
        al[3][2] = fmaf(xv.w, wl.z, al[3][2]); al[3][3] = fmaf(xv.w, wl.w, al[3][3]);
    }
    float4 bm = *(const float4*)&bmu[colq];
    float4 bl = *(const float4*)&bls[colq];
#pragma unroll
    for (int i = 0; i < 4; ++i) {
        int row = rowbase + rloc + i;
        if (row < n) {
            *(float4*)(mu + (size_t)row * 64 + colq) =
                make_float4(am[i][0] + bm.x, am[i][1] + bm.y, am[i][2] + bm.z, am[i][3] + bm.w);
            *(float4*)(ls + (size_t)row * 64 + colq) =
                make_float4(al[i][0] + bl.x, al[i][1] + bl.y, al[i][2] + bl.z, al[i][3] + bl.w);
        }
    }
}

extern "C" void kernel_launch(void* const* d_in, const int* in_sizes, int n_in,
                              void* d_out, int out_size, void* d_ws, size_t ws_size,
                              hipStream_t stream) {
    const float* x   = (const float*)d_in[0];
    const int*   ei  = (const int*)d_in[1];
    const float* W1  = (const float*)d_in[2];
    const float* b1  = (const float*)d_in[3];
    const float* Wmu = (const float*)d_in[4];
    const float* bmu = (const float*)d_in[5];
    const float* Wls = (const float*)d_in[6];
    const float* bls = (const float*)d_in[7];

    const int N = in_sizes[0] / 128;
    const int E = in_sizes[1] / 2;
    const int* src = ei;
    const int* dst = ei + E;

    const int nb = (N + BN - 1) / BN;   // 391 buckets (<= NB_MAX)

    float*  dinv   = (float*)d_ws;                      // N
    int*    rowptr = (int*)(dinv + N);                  // N+1
    int*    hist   = rowptr + ((N + 1 + 63) & ~63);     // SORT_BLOCKS*nb
    int*    btot   = hist + SORT_BLOCKS * nb;           // nb
    int*    bbase  = btot + ((nb + 63) & ~63);          // nb+1
    int*    ssrc   = bbase + ((nb + 1 + 63) & ~63);     // E
    uint*   bpk    = (uint*)(ssrc + E);                 // E
    ushort* T1     = (ushort*)(bpk + E);                // N*64 bf16
    ushort* T2     = T1 + (size_t)N * FEAT;             // N*64 bf16

    float* mu_slot = (float*)d_out;                     // N*64: Hagg then mu (in-place)
    float* ls_slot = mu_slot + (size_t)N * FEAT;        // N*64: ls

    const int TB = 256;
    int grid_n4 = (N + 3) / 4;
    int grid_g  = (N + 63) / 64;

    // ---- CSR build (no global atomics) ----
    hist_kernel<<<SORT_BLOCKS, TB, 0, stream>>>(dst, hist, E, nb);
    colscan_kernel<<<nb, TB, 0, stream>>>(hist, btot, nb);
    bbase_kernel<<<1, TB, 0, stream>>>(btot, bbase, nb, rowptr, N, E);
    sort_scatter_kernel<<<SORT_BLOCKS, TB, 0, stream>>>(src, dst, hist, bbase, bpk, E, nb);
    place_kernel<<<nb, TB, 0, stream>>>(bpk, bbase, rowptr, dinv, ssrc, N);

    // ---- T1 = bf16(dinv * (x@W1)) ----
    gemm1_kernel<<<grid_g, TB, 0, stream>>>(x, W1, dinv, T1, N);

    // ---- T2 = bf16(dinv * relu(dinv*aggsum(T1) + b1)) ----
    agg_kernel<0><<<grid_n4, TB, 0, stream>>>(T1, rowptr, ssrc, dinv, b1, T2, nullptr, N);

    // ---- Hagg = dinv * aggsum(T2) ----
    agg_kernel<1><<<grid_n4, TB, 0, stream>>>(T2, rowptr, ssrc, dinv, nullptr, nullptr, mu_slot, N);

    // ---- heads ----
    gemm_dual_kernel<<<grid_g, TB, 0, stream>>>(mu_slot, Wmu, bmu, Wls, bls, mu_slot, ls_slot, N);
}